// Round 2
// baseline (373.140 us; speedup 1.0000x reference)
//
#include <hip/hip_runtime.h>
#include <hip/hip_bf16.h>
#include <stdint.h>

#define F 1024

typedef __attribute__((ext_vector_type(4))) float f32x4;
typedef __attribute__((ext_vector_type(8))) short short8;
typedef __attribute__((ext_vector_type(8))) __bf16 bf16x8;
typedef __attribute__((ext_vector_type(4))) __bf16 bf16x4;

// ---------------- transpose logits -> logitsT ----------------
__global__ void transpose_k(const float* __restrict__ in, float* __restrict__ out) {
  __shared__ float tile[32][33];
  int bx = blockIdx.x, by = blockIdx.y;
  int tx = threadIdx.x & 31, ty = threadIdx.x >> 5;  // 32x8
  int x = bx * 32 + tx;
#pragma unroll
  for (int i = 0; i < 32; i += 8) {
    tile[ty + i][tx] = in[(size_t)(by * 32 + ty + i) * F + x];
  }
  __syncthreads();
  int xo = by * 32 + tx;
#pragma unroll
  for (int i = 0; i < 32; i += 8) {
    out[(size_t)(bx * 32 + ty + i) * F + xo] = tile[tx][ty + i];
  }
}

// ---------------- one Sinkhorn half-step: o[row] = LSE_c(M[row][c] - w[c]) ----------------
__global__ void lse_step_k(const float* __restrict__ M, const float* __restrict__ w,
                           float* __restrict__ o) {
  int row = blockIdx.x;
  int tid = threadIdx.x;
  int lane = tid & 63, wid = tid >> 6;
  const float* mr = M + (size_t)row * F;
  float vals[4];
  float mx = -1e30f;
#pragma unroll
  for (int i = 0; i < 4; ++i) {
    int c = tid + i * 256;
    vals[i] = mr[c] - w[c];
    mx = fmaxf(mx, vals[i]);
  }
#pragma unroll
  for (int off = 32; off; off >>= 1) mx = fmaxf(mx, __shfl_xor(mx, off));
  __shared__ float smx[4], ssum[4];
  if (lane == 0) smx[wid] = mx;
  __syncthreads();
  mx = fmaxf(fmaxf(smx[0], smx[1]), fmaxf(smx[2], smx[3]));
  float s = 0.f;
#pragma unroll
  for (int i = 0; i < 4; ++i) s += expf(vals[i] - mx);
#pragma unroll
  for (int off = 32; off; off >>= 1) s += __shfl_xor(s, off);
  if (lane == 0) ssum[wid] = s;
  __syncthreads();
  if (tid == 0) o[row] = mx + logf(ssum[0] + ssum[1] + ssum[2] + ssum[3]);
}

// ---------------- Delta^T = P^T - 1/1024 in bf16, pre-swizzled into per-tile linear images --
// Stored so that for (nblk, kstep) the 8KB GEMM B-tile [kk][n_local][j] is contiguous.
__global__ void pdelta_k(const float* __restrict__ LT, const float* __restrict__ u,
                         const float* __restrict__ v, __bf16* __restrict__ Bws) {
  int n = blockIdx.x, tid = threadIdx.x;
  float vn = v[n];
  const float* lt = LT + (size_t)n * F;
  int nblk = n >> 7, nl = n & 127;
#pragma unroll
  for (int i = 0; i < 4; ++i) {
    int k = tid + i * 256;
    float val = expf(lt[k] - u[k] - vn) - 0.0009765625f;
    size_t idx = ((size_t)((nblk * 32 + (k >> 5)) * 4 + ((k & 31) >> 3)) * 128 + nl) * 8 + (k & 7);
    Bws[idx] = (__bf16)val;
  }
}

// ---------------- GEMM: out[m][n] = c*rowsum_f32(x[m]) + sum_k bf16(x[m][k]) * DeltaT ------
__device__ inline void gload_lds16(const void* g, void* l) {
  __builtin_amdgcn_global_load_lds((const __attribute__((address_space(1))) void*)g,
                                   (__attribute__((address_space(3))) void*)l, 16, 0, 0);
}

__global__ __launch_bounds__(256) void gemm_k(const float* __restrict__ x,
                                              const __bf16* __restrict__ Bws,
                                              float* __restrict__ out) {
  __shared__ __attribute__((aligned(16))) __bf16 A_lds[4096];  // [kk][row][8]
  __shared__ __attribute__((aligned(16))) __bf16 B_lds[4096];  // [kk][n][8]
  __shared__ float crs[128];

  int bid = blockIdx.x;
  // XCD-chunked swizzle (4096 % 8 == 0 -> bijective); n fastest within a chunk.
  int swz = (bid & 7) * 512 + (bid >> 3);
  int mblk = swz >> 3;  // 0..511
  int nblk = swz & 7;   // 0..7

  int tid = threadIdx.x;
  int lane = tid & 63;
  int wid = tid >> 6;
  int wr = wid >> 1, wc = wid & 1;

  const int arow0 = tid >> 3;       // 0..31
  const int acol = (tid & 7) * 4;   // 0..28
  const int akk = acol >> 3;        // 0..3
  const int aj0 = acol & 7;         // 0 or 4

  const float* xp = x + (size_t)(mblk * 128 + arow0) * F + acol;
  const __bf16* bp = Bws + (size_t)nblk * (32 * 4096) + tid * 8;

  const f32x4 fz = {0.f, 0.f, 0.f, 0.f};
  f32x4 acc[4][4];
#pragma unroll
  for (int a = 0; a < 4; ++a)
#pragma unroll
    for (int b = 0; b < 4; ++b) acc[a][b] = fz;
  float rowsum[4] = {0.f, 0.f, 0.f, 0.f};

  for (int ks = 0; ks < 32; ++ks) {
    // A: 128x32 f32 loads (coalesced dwordx4)
    f32x4 av[4];
#pragma unroll
    for (int i = 0; i < 4; ++i)
      av[i] = *reinterpret_cast<const f32x4*>(xp + (size_t)i * 32 * F + ks * 32);
    // B: 8KB tile via global_load_lds (linear image, 2 x 16B per thread)
    gload_lds16(bp, (char*)B_lds + tid * 16);
    gload_lds16(bp + 2048, (char*)B_lds + 4096 + tid * 16);
    // A: convert + ds_write + exact f32 rowsum
#pragma unroll
    for (int i = 0; i < 4; ++i) {
      f32x4 a = av[i];
      rowsum[i] += (a.x + a.y) + (a.z + a.w);
      bf16x4 h;
      h.x = (__bf16)a.x; h.y = (__bf16)a.y; h.z = (__bf16)a.z; h.w = (__bf16)a.w;
      int row = arow0 + i * 32;
      *reinterpret_cast<bf16x4*>(&A_lds[(akk * 128 + row) * 8 + aj0]) = h;
    }
    __syncthreads();

    int kk = lane >> 4;
    int l15 = lane & 15;
    bf16x8 afrag[4], bfrag[4];
#pragma unroll
    for (int mf = 0; mf < 4; ++mf)
      afrag[mf] = *reinterpret_cast<const bf16x8*>(&A_lds[(kk * 128 + wr * 64 + mf * 16 + l15) * 8]);
#pragma unroll
    for (int nf = 0; nf < 4; ++nf)
      bfrag[nf] = *reinterpret_cast<const bf16x8*>(&B_lds[(kk * 128 + wc * 64 + nf * 16 + l15) * 8]);
#pragma unroll
    for (int mf = 0; mf < 4; ++mf)
#pragma unroll
      for (int nf = 0; nf < 4; ++nf)
        acc[mf][nf] = __builtin_amdgcn_mfma_f32_16x16x32_bf16(afrag[mf], bfrag[nf], acc[mf][nf], 0, 0, 0);
    __syncthreads();
    bp += 4096;
  }

  // rowsum reduce: 8 partials per row -> c * rowsum
  float* red = reinterpret_cast<float*>(A_lds);
#pragma unroll
  for (int i = 0; i < 4; ++i) red[(arow0 + i * 32) * 8 + (tid & 7)] = rowsum[i];
  __syncthreads();
  if (tid < 128) {
    float s = 0.f;
#pragma unroll
    for (int q = 0; q < 8; ++q) s += red[tid * 8 + q];
    crs[tid] = s * 0.0009765625f;
  }
  __syncthreads();

  size_t orow = (size_t)(mblk * 128);
  int col0 = nblk * 128 + wc * 64;
#pragma unroll
  for (int mf = 0; mf < 4; ++mf) {
    int row_l = wr * 64 + mf * 16 + (lane >> 4) * 4;
#pragma unroll
    for (int nf = 0; nf < 4; ++nf) {
      int col = col0 + nf * 16 + (lane & 15);
      f32x4 a = acc[mf][nf];
#pragma unroll
      for (int r = 0; r < 4; ++r) {
        out[(orow + row_l + r) * F + col] = a[r] + crs[row_l + r];
      }
    }
  }
}

extern "C" void kernel_launch(void* const* d_in, const int* in_sizes, int n_in,
                              void* d_out, int out_size, void* d_ws, size_t ws_size,
                              hipStream_t stream) {
  const float* x = (const float*)d_in[0];       // [65536,1024] f32
  const float* logits = (const float*)d_in[1];  // [1024,1024] f32
  float* out = (float*)d_out;                   // [65536,1024] f32

  char* ws = (char*)d_ws;
  float* logitsT = (float*)ws;                          // 4MB
  float* u = (float*)(ws + 4u * 1024 * 1024);           // 4KB
  float* v = u + 1024;                                  // 4KB
  __bf16* Bws = (__bf16*)(ws + 4u * 1024 * 1024 + 8192);  // 2MB

  hipMemsetAsync(v, 0, 1024 * sizeof(float), stream);
  transpose_k<<<dim3(32, 32), 256, 0, stream>>>(logits, logitsT);
  for (int it = 0; it < 10; ++it) {
    lse_step_k<<<1024, 256, 0, stream>>>(logits, v, u);    // row step: u
    lse_step_k<<<1024, 256, 0, stream>>>(logitsT, u, v);   // col step: v
  }
  pdelta_k<<<1024, 256, 0, stream>>>(logitsT, u, v, Bws);
  gemm_k<<<4096, 256, 0, stream>>>(x, Bws, out);
}

// Round 3
// 350.087 us; speedup vs baseline: 1.0658x; 1.0658x over previous
//
#include <hip/hip_runtime.h>
#include <hip/hip_bf16.h>
#include <stdint.h>

#define F 1024

typedef __attribute__((ext_vector_type(4))) float f32x4;
typedef __attribute__((ext_vector_type(8))) __bf16 bf16x8;
typedef __attribute__((ext_vector_type(4))) __bf16 bf16x4;

// ---------------- transpose logits -> logitsT ----------------
__global__ void transpose_k(const float* __restrict__ in, float* __restrict__ out) {
  __shared__ float tile[32][33];
  int bx = blockIdx.x, by = blockIdx.y;
  int tx = threadIdx.x & 31, ty = threadIdx.x >> 5;  // 32x8
  int x = bx * 32 + tx;
#pragma unroll
  for (int i = 0; i < 32; i += 8) {
    tile[ty + i][tx] = in[(size_t)(by * 32 + ty + i) * F + x];
  }
  __syncthreads();
  int xo = by * 32 + tx;
#pragma unroll
  for (int i = 0; i < 32; i += 8) {
    out[(size_t)(bx * 32 + ty + i) * F + xo] = tile[tx][ty + i];
  }
}

// ---------------- one Sinkhorn half-step: o[row] = LSE_c(M[row][c] - w[c]); w may be null ----
__global__ void lse_step_k(const float* __restrict__ M, const float* __restrict__ w,
                           float* __restrict__ o) {
  int row = blockIdx.x;
  int tid = threadIdx.x;
  int lane = tid & 63, wid = tid >> 6;
  const float* mr = M + (size_t)row * F;
  float vals[4];
  float mx = -1e30f;
#pragma unroll
  for (int i = 0; i < 4; ++i) {
    int c = tid + i * 256;
    float wv = w ? w[c] : 0.f;
    vals[i] = mr[c] - wv;
    mx = fmaxf(mx, vals[i]);
  }
#pragma unroll
  for (int off = 32; off; off >>= 1) mx = fmaxf(mx, __shfl_xor(mx, off));
  __shared__ float smx[4], ssum[4];
  if (lane == 0) smx[wid] = mx;
  __syncthreads();
  mx = fmaxf(fmaxf(smx[0], smx[1]), fmaxf(smx[2], smx[3]));
  float s = 0.f;
#pragma unroll
  for (int i = 0; i < 4; ++i) s += expf(vals[i] - mx);
#pragma unroll
  for (int off = 32; off; off >>= 1) s += __shfl_xor(s, off);
  if (lane == 0) ssum[wid] = s;
  __syncthreads();
  if (tid == 0) o[row] = mx + logf(ssum[0] + ssum[1] + ssum[2] + ssum[3]);
}

// ---------------- fused final col-step + Delta^T image build ------------------------------
// Block n: v_n = LSE_i(LT[n][i] - u[i]); then write bf16 Delta^T column n into the
// pre-swizzled per-tile linear image consumed by the GEMM's global_load_lds.
__global__ void colpdelta_k(const float* __restrict__ LT, const float* __restrict__ u,
                            __bf16* __restrict__ Bws) {
  int n = blockIdx.x;
  int tid = threadIdx.x;
  int lane = tid & 63, wid = tid >> 6;
  const float* mr = LT + (size_t)n * F;
  float vals[4];
  float mx = -1e30f;
#pragma unroll
  for (int i = 0; i < 4; ++i) {
    int c = tid + i * 256;
    vals[i] = mr[c] - u[c];
    mx = fmaxf(mx, vals[i]);
  }
#pragma unroll
  for (int off = 32; off; off >>= 1) mx = fmaxf(mx, __shfl_xor(mx, off));
  __shared__ float smx[4], ssum[4];
  __shared__ float svn;
  if (lane == 0) smx[wid] = mx;
  __syncthreads();
  mx = fmaxf(fmaxf(smx[0], smx[1]), fmaxf(smx[2], smx[3]));
  float s = 0.f;
#pragma unroll
  for (int i = 0; i < 4; ++i) s += expf(vals[i] - mx);
#pragma unroll
  for (int off = 32; off; off >>= 1) s += __shfl_xor(s, off);
  if (lane == 0) ssum[wid] = s;
  __syncthreads();
  if (tid == 0) svn = mx + logf(ssum[0] + ssum[1] + ssum[2] + ssum[3]);
  __syncthreads();
  float vn = svn;
  int nblk = n >> 7, nl = n & 127;
#pragma unroll
  for (int i = 0; i < 4; ++i) {
    int k = tid + i * 256;
    float val = expf(vals[i] - vn) - 0.0009765625f;
    size_t idx = ((size_t)((nblk * 32 + (k >> 5)) * 4 + ((k & 31) >> 3)) * 128 + nl) * 8 + (k & 7);
    Bws[idx] = (__bf16)val;
  }
}

// ---------------- conv pass: x f32 -> bf16 (chunk-XOR-swizzled rows) + exact f32 rowsum ----
// Row layout: row m = 128 chunks of 16B; chunk for (ks,kk) stored at position
// ks*4 + (kk ^ ((m>>1)&3)) so GEMM ds_read_b128 fragments are bank-clean.
__global__ void conv_k(const float* __restrict__ x, __bf16* __restrict__ xs,
                       float* __restrict__ rs) {
  int t = threadIdx.x;
  int rl = t >> 7;    // 0..1
  int ck = t & 127;   // chunk id 0..127
  size_t m = (size_t)blockIdx.x * 2 + rl;
  const float* xp = x + m * F + ck * 8;
  f32x4 a = *reinterpret_cast<const f32x4*>(xp);
  f32x4 b = *reinterpret_cast<const f32x4*>(xp + 4);
  float s = ((a.x + a.y) + (a.z + a.w)) + ((b.x + b.y) + (b.z + b.w));
  bf16x8 h;
  h[0] = (__bf16)a.x; h[1] = (__bf16)a.y; h[2] = (__bf16)a.z; h[3] = (__bf16)a.w;
  h[4] = (__bf16)b.x; h[5] = (__bf16)b.y; h[6] = (__bf16)b.z; h[7] = (__bf16)b.w;
  int ks = ck >> 2, kk = ck & 3;
  int p = kk ^ ((int)(m >> 1) & 3);
  *reinterpret_cast<bf16x8*>(xs + m * F + ks * 32 + p * 8) = h;
  // exact-f32 rowsum (each row spans 2 waves)
#pragma unroll
  for (int off = 32; off; off >>= 1) s += __shfl_xor(s, off);
  __shared__ float pr[4];
  if ((t & 63) == 0) pr[t >> 6] = s;
  __syncthreads();
  if (t == 0) rs[m] = pr[0] + pr[1];
  if (t == 128) rs[m] = pr[2] + pr[3];
}

// ---------------- GEMM: out = bf16(x) @ DeltaT + c*rowsum_f32(x), A&B via global_load_lds --
__device__ inline void gload_lds16(const void* g, void* l) {
  __builtin_amdgcn_global_load_lds((const __attribute__((address_space(1))) void*)g,
                                   (__attribute__((address_space(3))) void*)l, 16, 0, 0);
}

__global__ __launch_bounds__(256) void gemm_k(const __bf16* __restrict__ xs,
                                              const __bf16* __restrict__ Bws,
                                              const float* __restrict__ rs,
                                              float* __restrict__ out) {
  __shared__ __attribute__((aligned(16))) __bf16 A_lds[4096];  // [row][4 chunks, XOR-pos]
  __shared__ __attribute__((aligned(16))) __bf16 B_lds[4096];  // [kk][n][8]
  __shared__ float crs[128];

  int bid = blockIdx.x;
  // XCD-chunked swizzle (4096 % 8 == 0 -> bijective); n fastest within a chunk.
  int swz = (bid & 7) * 512 + (bid >> 3);
  int mblk = swz >> 3;  // 0..511
  int nblk = swz & 7;   // 0..7

  int tid = threadIdx.x;
  int lane = tid & 63;
  int wid = tid >> 6;
  int wr = wid >> 1, wc = wid & 1;

  size_t m0 = (size_t)mblk * 128;
  // A staging: chunk t-lin = (wid*2+i)*64 + lane -> row = t>>2, pos = lane&3 (already
  // swizzled in global). Per-lane global addr, linear LDS dest.
  const __bf16* ga0 = xs + (m0 + wid * 32 + (lane >> 2)) * F + (lane & 3) * 8;
  const __bf16* ga1 = ga0 + (size_t)16 * F;
  char* da0 = (char*)A_lds + (wid * 2 + 0) * 1024 + lane * 16;
  char* da1 = (char*)A_lds + (wid * 2 + 1) * 1024 + lane * 16;
  const __bf16* bp = Bws + (size_t)nblk * (32 * 4096) + tid * 8;
  char* db0 = (char*)B_lds + tid * 16;
  char* db1 = (char*)B_lds + 4096 + tid * 16;

  if (tid < 128) crs[tid] = 0.0009765625f * rs[m0 + tid];

  const f32x4 fz = {0.f, 0.f, 0.f, 0.f};
  f32x4 acc[4][4];
#pragma unroll
  for (int a = 0; a < 4; ++a)
#pragma unroll
    for (int b = 0; b < 4; ++b) acc[a][b] = fz;

  int kk = lane >> 4;
  int l15 = lane & 15;
  int pA = kk ^ ((l15 >> 1) & 3);  // XOR-swizzled chunk position (mf*16, wr*64 are mult of 8)

  for (int ks = 0; ks < 32; ++ks) {
    gload_lds16(ga0 + ks * 32, da0);
    gload_lds16(ga1 + ks * 32, da1);
    gload_lds16(bp, db0);
    gload_lds16(bp + 2048, db1);
    __syncthreads();

    bf16x8 afrag[4], bfrag[4];
#pragma unroll
    for (int mf = 0; mf < 4; ++mf) {
      int row = wr * 64 + mf * 16 + l15;
      afrag[mf] = *reinterpret_cast<const bf16x8*>(&A_lds[row * 32 + pA * 8]);
    }
#pragma unroll
    for (int nf = 0; nf < 4; ++nf)
      bfrag[nf] = *reinterpret_cast<const bf16x8*>(&B_lds[(kk * 128 + wc * 64 + nf * 16 + l15) * 8]);
#pragma unroll
    for (int mf = 0; mf < 4; ++mf)
#pragma unroll
      for (int nf = 0; nf < 4; ++nf)
        acc[mf][nf] = __builtin_amdgcn_mfma_f32_16x16x32_bf16(afrag[mf], bfrag[nf], acc[mf][nf], 0, 0, 0);
    __syncthreads();
    bp += 4096;
  }

  size_t orow = m0;
  int col0 = nblk * 128 + wc * 64;
#pragma unroll
  for (int mf = 0; mf < 4; ++mf) {
    int row_l = wr * 64 + mf * 16 + (lane >> 4) * 4;
#pragma unroll
    for (int nf = 0; nf < 4; ++nf) {
      int col = col0 + nf * 16 + (lane & 15);
      f32x4 a = acc[mf][nf];
#pragma unroll
      for (int r = 0; r < 4; ++r) {
        out[(orow + row_l + r) * F + col] = a[r] + crs[row_l + r];
      }
    }
  }
}

// ---------------- fallback GEMM (fused f32 A-path) if ws is too small for x_bf16 ----------
__global__ __launch_bounds__(256) void gemm_fused_k(const float* __restrict__ x,
                                                    const __bf16* __restrict__ Bws,
                                                    float* __restrict__ out) {
  __shared__ __attribute__((aligned(16))) __bf16 A_lds[4096];
  __shared__ __attribute__((aligned(16))) __bf16 B_lds[4096];
  __shared__ float crs[128];

  int bid = blockIdx.x;
  int swz = (bid & 7) * 512 + (bid >> 3);
  int mblk = swz >> 3, nblk = swz & 7;
  int tid = threadIdx.x, lane = tid & 63, wid = tid >> 6;
  int wr = wid >> 1, wc = wid & 1;

  const int arow0 = tid >> 3;
  const int acol = (tid & 7) * 4;
  const int akk = acol >> 3;
  const int aj0 = acol & 7;

  const float* xp = x + (size_t)(mblk * 128 + arow0) * F + acol;
  const __bf16* bp = Bws + (size_t)nblk * (32 * 4096) + tid * 8;

  const f32x4 fz = {0.f, 0.f, 0.f, 0.f};
  f32x4 acc[4][4];
#pragma unroll
  for (int a = 0; a < 4; ++a)
#pragma unroll
    for (int b = 0; b < 4; ++b) acc[a][b] = fz;
  float rowsum[4] = {0.f, 0.f, 0.f, 0.f};

  for (int ks = 0; ks < 32; ++ks) {
    f32x4 av[4];
#pragma unroll
    for (int i = 0; i < 4; ++i)
      av[i] = *reinterpret_cast<const f32x4*>(xp + (size_t)i * 32 * F + ks * 32);
    gload_lds16(bp, (char*)B_lds + tid * 16);
    gload_lds16(bp + 2048, (char*)B_lds + 4096 + tid * 16);
#pragma unroll
    for (int i = 0; i < 4; ++i) {
      f32x4 a = av[i];
      rowsum[i] += (a.x + a.y) + (a.z + a.w);
      bf16x4 h;
      h.x = (__bf16)a.x; h.y = (__bf16)a.y; h.z = (__bf16)a.z; h.w = (__bf16)a.w;
      int row = arow0 + i * 32;
      *reinterpret_cast<bf16x4*>(&A_lds[(akk * 128 + row) * 8 + aj0]) = h;
    }
    __syncthreads();

    int kk = lane >> 4;
    int l15 = lane & 15;
    bf16x8 afrag[4], bfrag[4];
#pragma unroll
    for (int mf = 0; mf < 4; ++mf)
      afrag[mf] = *reinterpret_cast<const bf16x8*>(&A_lds[(kk * 128 + wr * 64 + mf * 16 + l15) * 8]);
#pragma unroll
    for (int nf = 0; nf < 4; ++nf)
      bfrag[nf] = *reinterpret_cast<const bf16x8*>(&B_lds[(kk * 128 + wc * 64 + nf * 16 + l15) * 8]);
#pragma unroll
    for (int mf = 0; mf < 4; ++mf)
#pragma unroll
      for (int nf = 0; nf < 4; ++nf)
        acc[mf][nf] = __builtin_amdgcn_mfma_f32_16x16x32_bf16(afrag[mf], bfrag[nf], acc[mf][nf], 0, 0, 0);
    __syncthreads();
    bp += 4096;
  }

  float* red = reinterpret_cast<float*>(A_lds);
#pragma unroll
  for (int i = 0; i < 4; ++i) red[(arow0 + i * 32) * 8 + (tid & 7)] = rowsum[i];
  __syncthreads();
  if (tid < 128) {
    float s = 0.f;
#pragma unroll
    for (int q = 0; q < 8; ++q) s += red[tid * 8 + q];
    crs[tid] = s * 0.0009765625f;
  }
  __syncthreads();

  size_t orow = (size_t)(mblk * 128);
  int col0 = nblk * 128 + wc * 64;
#pragma unroll
  for (int mf = 0; mf < 4; ++mf) {
    int row_l = wr * 64 + mf * 16 + (lane >> 4) * 4;
#pragma unroll
    for (int nf = 0; nf < 4; ++nf) {
      int col = col0 + nf * 16 + (lane & 15);
      f32x4 a = acc[mf][nf];
#pragma unroll
      for (int r = 0; r < 4; ++r) {
        out[(orow + row_l + r) * F + col] = a[r] + crs[row_l + r];
      }
    }
  }
}

extern "C" void kernel_launch(void* const* d_in, const int* in_sizes, int n_in,
                              void* d_out, int out_size, void* d_ws, size_t ws_size,
                              hipStream_t stream) {
  const float* x = (const float*)d_in[0];       // [65536,1024] f32
  const float* logits = (const float*)d_in[1];  // [1024,1024] f32
  float* out = (float*)d_out;                   // [65536,1024] f32

  char* ws = (char*)d_ws;
  float* logitsT = (float*)ws;                              // 4MB
  float* u = (float*)(ws + 4u * 1024 * 1024);               // 4KB
  float* v = u + 1024;                                      // 4KB
  __bf16* Bws = (__bf16*)(ws + 4u * 1024 * 1024 + 8192);    // 2MB
  float* rs = (float*)(ws + 6u * 1024 * 1024 + 8192);       // 256KB rowsums
  __bf16* xs = (__bf16*)(ws + 6u * 1024 * 1024 + 8192 + 256u * 1024);  // 128MB bf16 x
  size_t need = 6u * 1024 * 1024 + 8192 + 256u * 1024 + 128u * 1024 * 1024;

  bool big = ws_size >= need;
  if (big) conv_k<<<32768, 256, 0, stream>>>(x, xs, rs);  // overlappable prologue work
  // Sinkhorn: first row-step has v=0 (null), so no memset launch needed.
  lse_step_k<<<1024, 256, 0, stream>>>(logits, nullptr, u);
  transpose_k<<<dim3(32, 32), 256, 0, stream>>>(logits, logitsT);
  for (int it = 0; it < 9; ++it) {
    lse_step_k<<<1024, 256, 0, stream>>>(logitsT, u, v);   // col step: v
    lse_step_k<<<1024, 256, 0, stream>>>(logits, v, u);    // row step: u
  }
  colpdelta_k<<<1024, 256, 0, stream>>>(logitsT, u, Bws);  // final col step + Delta image

  if (big) {
    gemm_k<<<4096, 256, 0, stream>>>(xs, Bws, rs, out);
  } else {
    gemm_fused_k<<<4096, 256, 0, stream>>>(x, Bws, out);
  }
}

// Round 4
// 298.428 us; speedup vs baseline: 1.2504x; 1.1731x over previous
//
#include <hip/hip_runtime.h>
#include <hip/hip_bf16.h>
#include <stdint.h>

#define F 1024

typedef __attribute__((ext_vector_type(4))) float f32x4;
typedef __attribute__((ext_vector_type(8))) __bf16 bf16x8;

// ---------------- transpose logits -> logitsT ----------------
__global__ void transpose_k(const float* __restrict__ in, float* __restrict__ out) {
  __shared__ float tile[32][33];
  int bx = blockIdx.x, by = blockIdx.y;
  int tx = threadIdx.x & 31, ty = threadIdx.x >> 5;  // 32x8
  int x = bx * 32 + tx;
#pragma unroll
  for (int i = 0; i < 32; i += 8) {
    tile[ty + i][tx] = in[(size_t)(by * 32 + ty + i) * F + x];
  }
  __syncthreads();
  int xo = by * 32 + tx;
#pragma unroll
  for (int i = 0; i < 32; i += 8) {
    out[(size_t)(bx * 32 + ty + i) * F + xo] = tile[tx][ty + i];
  }
}

// ---------------- Sinkhorn half-step: o[row] = LSE_c(M[row][c] - w[c]); w may be null ------
__global__ void lse_step_k(const float* __restrict__ M, const float* __restrict__ w,
                           float* __restrict__ o) {
  int row = blockIdx.x;
  int tid = threadIdx.x;
  int lane = tid & 63, wid = tid >> 6;
  const float* mr = M + (size_t)row * F;
  float vals[4];
  float mx = -1e30f;
#pragma unroll
  for (int i = 0; i < 4; ++i) {
    int c = tid + i * 256;
    float wv = w ? w[c] : 0.f;
    vals[i] = mr[c] - wv;
    mx = fmaxf(mx, vals[i]);
  }
#pragma unroll
  for (int off = 32; off; off >>= 1) mx = fmaxf(mx, __shfl_xor(mx, off));
  __shared__ float smx[4], ssum[4];
  if (lane == 0) smx[wid] = mx;
  __syncthreads();
  mx = fmaxf(fmaxf(smx[0], smx[1]), fmaxf(smx[2], smx[3]));
  float s = 0.f;
#pragma unroll
  for (int i = 0; i < 4; ++i) s += expf(vals[i] - mx);
#pragma unroll
  for (int off = 32; off; off >>= 1) s += __shfl_xor(s, off);
  if (lane == 0) ssum[wid] = s;
  __syncthreads();
  if (tid == 0) o[row] = mx + logf(ssum[0] + ssum[1] + ssum[2] + ssum[3]);
}

// ---------------- fused final col-step + Delta^T B-images -------------------------------
// B image for (nb,t,qn): 1024 chunks of 16B, chunk (kc*128 + c') = DeltaT[n][t*64+kc*8..+8]
// where n = nb*256 + wn*64 + qn*32 + (c'&31), wn = c'>>5.
__global__ void colpdelta_k(const float* __restrict__ LT, const float* __restrict__ u,
                            __bf16* __restrict__ Bws) {
  int n = blockIdx.x;
  int tid = threadIdx.x;
  int lane = tid & 63, wid = tid >> 6;
  const float* mr = LT + (size_t)n * F;
  float vals[4];
  float mx = -1e30f;
#pragma unroll
  for (int i = 0; i < 4; ++i) {
    int c = tid + i * 256;
    vals[i] = mr[c] - u[c];
    mx = fmaxf(mx, vals[i]);
  }
#pragma unroll
  for (int off = 32; off; off >>= 1) mx = fmaxf(mx, __shfl_xor(mx, off));
  __shared__ float smx[4], ssum[4];
  __shared__ float svn;
  if (lane == 0) smx[wid] = mx;
  __syncthreads();
  mx = fmaxf(fmaxf(smx[0], smx[1]), fmaxf(smx[2], smx[3]));
  float s = 0.f;
#pragma unroll
  for (int i = 0; i < 4; ++i) s += expf(vals[i] - mx);
#pragma unroll
  for (int off = 32; off; off >>= 1) s += __shfl_xor(s, off);
  if (lane == 0) ssum[wid] = s;
  __syncthreads();
  if (tid == 0) svn = mx + logf(ssum[0] + ssum[1] + ssum[2] + ssum[3]);
  __syncthreads();
  float vn = svn;
  int nb = n >> 8, Np = n & 255;
  int qn = (Np >> 5) & 1;
  int cp = ((Np >> 6) & 3) * 32 + (Np & 31);
#pragma unroll
  for (int i = 0; i < 4; ++i) {
    int k = tid + i * 256;
    float val = expf(vals[i] - vn) - 0.0009765625f;
    int t = k >> 6, kc = (k >> 3) & 7, j = k & 7;
    size_t idx = (((size_t)(nb * 16 + t) * 2 + qn) * 1024 + kc * 128 + cp) * 8 + j;
    Bws[idx] = (__bf16)val;
  }
}

// ---------------- conv: x f32 -> bf16 A-images + exact f32 rowsum --------------------------
// A image for (mb,t,qm): chunk (r'*8 + kc'), r' = wm*64 + (m&63), kc' = kc ^ (m&7),
// holding x[mb*256 + wm*128 + qm*64 + (m&63)][t*64 + kc*8 .. +8].
__global__ void conv_k(const float* __restrict__ x, __bf16* __restrict__ xs,
                       float* __restrict__ rs) {
  int t = threadIdx.x;
  int rl = t >> 7;    // 0..1
  int q = t & 127;    // k-chunk 0..127
  size_t m = (size_t)blockIdx.x * 2 + rl;
  const float* xp = x + m * F + q * 8;
  f32x4 a = *reinterpret_cast<const f32x4*>(xp);
  f32x4 b = *reinterpret_cast<const f32x4*>(xp + 4);
  float s = ((a.x + a.y) + (a.z + a.w)) + ((b.x + b.y) + (b.z + b.w));
  bf16x8 h;
  h[0] = (__bf16)a.x; h[1] = (__bf16)a.y; h[2] = (__bf16)a.z; h[3] = (__bf16)a.w;
  h[4] = (__bf16)b.x; h[5] = (__bf16)b.y; h[6] = (__bf16)b.z; h[7] = (__bf16)b.w;
  int mb = (int)(m >> 8);
  int R = (int)(m & 255);
  int qm = (R >> 6) & 1;
  int rp = ((R >> 7) << 6) | (R & 63);
  int tt = q >> 3, kc = q & 7;
  int kcp = kc ^ (rp & 7);
  size_t idx = (((size_t)(mb * 16 + tt) * 2 + qm) * 1024 + rp * 8 + kcp) * 8;
  *reinterpret_cast<bf16x8*>(xs + idx) = h;
#pragma unroll
  for (int off = 32; off; off >>= 1) s += __shfl_xor(s, off);
  __shared__ float pr[4];
  if ((t & 63) == 0) pr[t >> 6] = s;
  __syncthreads();
  if (t == 0) rs[m] = pr[0] + pr[1];
  if (t == 128) rs[m] = pr[2] + pr[3];
}

// ---------------- 256x256 8-phase GEMM -----------------------------------------------------
__device__ __forceinline__ void gload16(const void* g, void* l) {
  __builtin_amdgcn_global_load_lds((const __attribute__((address_space(1))) void*)g,
                                   (__attribute__((address_space(3))) void*)l, 16, 0, 0);
}

#define MFMA16 __builtin_amdgcn_mfma_f32_16x16x32_bf16
#define BAR() __builtin_amdgcn_s_barrier()
#define PRIO1() __builtin_amdgcn_s_setprio(1)
#define PRIO0() __builtin_amdgcn_s_setprio(0)
#define VMW(N) asm volatile("s_waitcnt vmcnt(" #N ")" ::: "memory")

template<int D, int HM>
__device__ __forceinline__ void readA(const char* lds, int aBase, int aXor, bf16x8 (&aF)[4][2]) {
#pragma unroll
  for (int af = 0; af < 4; ++af) {
    const int base = (D << 15) + (HM << 14) + (af << 11);
    aF[af][0] = *reinterpret_cast<const bf16x8*>(lds + aBase + base + aXor);
    aF[af][1] = *reinterpret_cast<const bf16x8*>(lds + aBase + base + (aXor ^ 64));
  }
}

template<int D, int QN>
__device__ __forceinline__ void readB(const char* lds, int bBase, bf16x8 (&bF)[2][2]) {
#pragma unroll
  for (int bf = 0; bf < 2; ++bf) {
    const int base = (D << 15) + (QN << 14) + (bf << 8);
    bF[bf][0] = *reinterpret_cast<const bf16x8*>(lds + bBase + base);
    bF[bf][1] = *reinterpret_cast<const bf16x8*>(lds + bBase + base + 8192);
  }
}

template<int HM, int QN>
__device__ __forceinline__ void mfmaQ(bf16x8 (&aF)[4][2], bf16x8 (&bF)[2][2], f32x4 (&acc)[8][4]) {
#pragma unroll
  for (int af = 0; af < 4; ++af)
#pragma unroll
    for (int bf = 0; bf < 2; ++bf) {
      acc[HM * 4 + af][QN * 2 + bf] =
          MFMA16(aF[af][0], bF[bf][0], acc[HM * 4 + af][QN * 2 + bf], 0, 0, 0);
      acc[HM * 4 + af][QN * 2 + bf] =
          MFMA16(aF[af][1], bF[bf][1], acc[HM * 4 + af][QN * 2 + bf], 0, 0, 0);
    }
}

__global__ __launch_bounds__(512, 2) void gemm8_k(const __bf16* __restrict__ xs,
                                                  const __bf16* __restrict__ Bws,
                                                  const float* __restrict__ rs,
                                                  float* __restrict__ out) {
  extern __shared__ char lds[];
  const int tid = threadIdx.x;
  const int lane = tid & 63;
  const int wid = tid >> 6;
  const int wm = wid >> 2;  // 0..1
  const int wn = wid & 3;   // 0..3
  const int l15 = lane & 15;
  const int kk = lane >> 4;
  const int tid16 = tid * 16;

  int bid = blockIdx.x;
  int swz = (bid & 7) * 128 + (bid >> 3);  // XCD-chunked, bijective (1024%8==0)
  int mb = swz >> 2;  // 0..255
  int nb = swz & 3;   // 0..3

  const char* xa = (const char*)xs + (size_t)mb * 524288;
  const char* bw = (const char*)Bws + (size_t)nb * 524288;

  // crs -> LDS[131072..]
  if (tid < 256) {
    float v = rs[(size_t)mb * 256 + tid];
    *reinterpret_cast<float*>(lds + 131072 + tid * 4) = v * 0.0009765625f;
  }

  const int aBase = wm * 8192 + l15 * 128;
  const int aXor = (kk ^ (l15 & 7)) * 16;
  const int bBase = 65536 + wn * 512 + l15 * 16 + kk * 2048;

#define STG(gimg, lbase) do { \
    gload16((gimg) + tid16, lds + (lbase) + tid16); \
    gload16((gimg) + 8192 + tid16, lds + (lbase) + 8192 + tid16); } while (0)

  // Prologue: buf0 <- tile0 (all 4 regions), buf1 <- B-q0(t=1), A-q1(t=1)
  STG(xa + 0, 0);          // A(0,q0)
  STG(xa + 16384, 16384);  // A(0,q1)
  STG(bw + 0, 65536);      // B(0,q0)
  STG(bw + 16384, 81920);  // B(0,q1)
  STG(bw + 32768, 98304);  // B(1,q0)
  STG(xa + 49152, 49152);  // A(1,q1)
  asm volatile("s_waitcnt vmcnt(4) lgkmcnt(0)" ::: "memory");
  BAR();

  f32x4 acc[8][4];
#pragma unroll
  for (int a = 0; a < 8; ++a)
#pragma unroll
    for (int b = 0; b < 4; ++b) acc[a][b] = (f32x4){0.f, 0.f, 0.f, 0.f};
  bf16x8 aF[4][2], bF[2][2];

  for (int j = 0; j < 7; ++j) {
    const char* xt1 = xa + (size_t)(2 * j + 1) * 32768;
    const char* xt2 = xa + (size_t)(2 * j + 2) * 32768;
    const char* xt3 = xa + (size_t)(2 * j + 3) * 32768;
    const char* bt1 = bw + (size_t)(2 * j + 1) * 32768;
    const char* bt2 = bw + (size_t)(2 * j + 2) * 32768;
    const char* bt3 = bw + (size_t)(2 * j + 3) * 32768;
    // P1
    readA<0, 0>(lds, aBase, aXor, aF); readB<0, 0>(lds, bBase, bF);
    STG(xt1 + 0, 32768);
    BAR(); PRIO1(); mfmaQ<0, 0>(aF, bF, acc); PRIO0(); BAR();
    // P2
    readA<0, 1>(lds, aBase, aXor, aF);
    STG(bt1 + 16384, 114688);
    BAR(); PRIO1(); mfmaQ<1, 0>(aF, bF, acc); PRIO0(); VMW(8); BAR();
    // P3
    readB<0, 1>(lds, bBase, bF);
    STG(bt2 + 0, 65536);
    BAR(); PRIO1(); mfmaQ<1, 1>(aF, bF, acc); PRIO0(); BAR();
    // P4
    readA<0, 0>(lds, aBase, aXor, aF);
    STG(xt2 + 16384, 16384);
    BAR(); PRIO1(); mfmaQ<0, 1>(aF, bF, acc); PRIO0(); VMW(6); BAR();
    // P5
    readA<1, 0>(lds, aBase, aXor, aF); readB<1, 0>(lds, bBase, bF);
    STG(xt2 + 0, 0);
    BAR(); PRIO1(); mfmaQ<0, 0>(aF, bF, acc); PRIO0(); BAR();
    // P6
    readA<1, 1>(lds, aBase, aXor, aF);
    STG(bt2 + 16384, 81920);
    BAR(); PRIO1(); mfmaQ<1, 0>(aF, bF, acc); PRIO0(); VMW(8); BAR();
    // P7
    readB<1, 1>(lds, bBase, bF);
    STG(bt3 + 0, 98304);
    BAR(); PRIO1(); mfmaQ<1, 1>(aF, bF, acc); PRIO0(); BAR();
    // P8
    readA<1, 0>(lds, aBase, aXor, aF);
    STG(xt3 + 16384, 49152);
    BAR(); PRIO1(); mfmaQ<0, 1>(aF, bF, acc); PRIO0(); VMW(6); BAR();
  }
  // Peeled iter 7 (tiles 14,15): stages only P1,P2; drain 8 -> 2 -> 0.
  {
    const char* xt1 = xa + (size_t)15 * 32768;
    const char* bt1 = bw + (size_t)15 * 32768;
    readA<0, 0>(lds, aBase, aXor, aF); readB<0, 0>(lds, bBase, bF);
    STG(xt1 + 0, 32768);
    BAR(); PRIO1(); mfmaQ<0, 0>(aF, bF, acc); PRIO0(); BAR();
    readA<0, 1>(lds, aBase, aXor, aF);
    STG(bt1 + 16384, 114688);
    BAR(); PRIO1(); mfmaQ<1, 0>(aF, bF, acc); PRIO0(); VMW(8); BAR();
    readB<0, 1>(lds, bBase, bF);
    BAR(); PRIO1(); mfmaQ<1, 1>(aF, bF, acc); PRIO0(); BAR();
    readA<0, 0>(lds, aBase, aXor, aF);
    BAR(); PRIO1(); mfmaQ<0, 1>(aF, bF, acc); PRIO0(); VMW(2); BAR();
    readA<1, 0>(lds, aBase, aXor, aF); readB<1, 0>(lds, bBase, bF);
    BAR(); PRIO1(); mfmaQ<0, 0>(aF, bF, acc); PRIO0(); BAR();
    readA<1, 1>(lds, aBase, aXor, aF);
    BAR(); PRIO1(); mfmaQ<1, 0>(aF, bF, acc); PRIO0(); VMW(0); BAR();
    readB<1, 1>(lds, bBase, bF);
    BAR(); PRIO1(); mfmaQ<1, 1>(aF, bF, acc); PRIO0(); BAR();
    readA<1, 0>(lds, aBase, aXor, aF);
    BAR(); PRIO1(); mfmaQ<0, 1>(aF, bF, acc); PRIO0(); BAR();
  }

  // Epilogue: add rank-1 term, store (a, r, b order for write-combining)
  const size_t m0 = (size_t)mb * 256;
  const int ncol0 = nb * 256 + wn * 64 + l15;
  const float* crs = reinterpret_cast<const float*>(lds + 131072);
#pragma unroll
  for (int a = 0; a < 8; ++a) {
    int rbase = wm * 128 + a * 16 + kk * 4;
#pragma unroll
    for (int r = 0; r < 4; ++r) {
      float cv = crs[rbase + r];
      float* orow = out + (m0 + rbase + r) * F + ncol0;
#pragma unroll
      for (int b = 0; b < 4; ++b) {
        orow[b * 16] = acc[a][b][r] + cv;
      }
    }
  }
}

extern "C" void kernel_launch(void* const* d_in, const int* in_sizes, int n_in,
                              void* d_out, int out_size, void* d_ws, size_t ws_size,
                              hipStream_t stream) {
  const float* x = (const float*)d_in[0];       // [65536,1024] f32
  const float* logits = (const float*)d_in[1];  // [1024,1024] f32
  float* out = (float*)d_out;                   // [65536,1024] f32

  char* ws = (char*)d_ws;
  float* logitsT = (float*)ws;                              // 4MB
  float* u = (float*)(ws + 4u * 1024 * 1024);               // 4KB
  float* v = u + 1024;                                      // 4KB
  __bf16* Bws = (__bf16*)(ws + 4u * 1024 * 1024 + 8192);    // 2MB (B images)
  float* rs = (float*)(ws + 6u * 1024 * 1024 + 8192);       // 256KB rowsums
  __bf16* xs = (__bf16*)(ws + 6u * 1024 * 1024 + 8192 + 256u * 1024);  // 128MB A images

  hipFuncSetAttribute((const void*)gemm8_k, hipFuncAttributeMaxDynamicSharedMemorySize,
                      132096);

  conv_k<<<32768, 256, 0, stream>>>(x, xs, rs);
  lse_step_k<<<1024, 256, 0, stream>>>(logits, nullptr, u);
  transpose_k<<<dim3(32, 32), 256, 0, stream>>>(logits, logitsT);
  for (int it = 0; it < 9; ++it) {
    lse_step_k<<<1024, 256, 0, stream>>>(logitsT, u, v);   // col step
    lse_step_k<<<1024, 256, 0, stream>>>(logits, v, u);    // row step
  }
  colpdelta_k<<<1024, 256, 0, stream>>>(logitsT, u, Bws);  // final col step + B images
  gemm8_k<<<1024, 512, 132096, stream>>>(xs, Bws, rs, out);
}